// Round 12
// baseline (265.145 us; speedup 1.0000x reference)
//
#include <hip/hip_runtime.h>
#include <math.h>

#define NN 50000
#define NE 600000
#define D 128
#define NH 3
#define SCAN_BLOCKS ((NN + 255) / 256)   // 196
#define GEMM_BLOCKS ((NN + 63) / 64)     // 782
#define GEMM_THREADS (GEMM_BLOCKS * 256) // 200192

typedef short bf16x8 __attribute__((ext_vector_type(8)));
typedef float f32x4 __attribute__((ext_vector_type(4)));

__device__ __forceinline__ unsigned short f2b(float f) {
  unsigned int u = __float_as_uint(f);
  u += 0x7FFF + ((u >> 16) & 1);          // round-to-nearest-even
  return (unsigned short)(u >> 16);
}
__device__ __forceinline__ float blo(unsigned int u) {
  return __uint_as_float(u << 16);
}
__device__ __forceinline__ float bhi(unsigned int u) {
  return __uint_as_float(u & 0xffff0000u);
}

// ---------------------------------------------------------------------------
// pack_all: one kernel, block-role dispatch (unchanged from r11, proven).
// ---------------------------------------------------------------------------
__global__ __launch_bounds__(256) void pack_all(const float* __restrict__ W_lin,
                                                const float* __restrict__ W_heads,
                                                const float* __restrict__ att_src,
                                                const float* __restrict__ att_dst,
                                                const float* __restrict__ b_lin,
                                                uint4* __restrict__ Bpack,
                                                float* __restrict__ bcomb,
                                                float* __restrict__ sbuf,
                                                int* __restrict__ counts) {
  const int bx = blockIdx.x;
  const int tid = threadIdx.x;
  if (bx < 24) {
    int u = bx * 256 + tid;            // < 6144
    int h = u >> 11, r = u & 2047;
    int nt = r >> 8, s = (r >> 6) & 3, q = (r >> 4) & 3, n0 = r & 15;
    int kbase = s * 32 + q * 8;
    int n = nt * 16 + n0;
    const float* wl = W_lin + kbase * D;
    const float* wh = W_heads + h * D * D + n;
    float vals[8];
    #pragma unroll
    for (int j = 0; j < 8; ++j) vals[j] = 0.f;
    for (int m = 0; m < D; ++m) {
      float whv = wh[m * D];
      #pragma unroll
      for (int j = 0; j < 8; ++j) vals[j] += wl[j * D + m] * whv;
    }
    unsigned int w[4];
    #pragma unroll
    for (int p = 0; p < 4; ++p)
      w[p] = (unsigned int)f2b(vals[2 * p]) | ((unsigned int)f2b(vals[2 * p + 1]) << 16);
    Bpack[h * 2304 + r] = make_uint4(w[0], w[1], w[2], w[3]);
  } else if (bx < 27) {
    const int h = bx - 24;
    __shared__ float wha_s[128], wha_d[128], scs[128], scd[128];
    {
      int m = tid & 127;
      const float* W = W_heads + h * D * D + m * D;
      const float* a = (tid < 128) ? (att_src + h * D) : (att_dst + h * D);
      float acc = 0.f;
      for (int n = 0; n < D; ++n) acc += W[n] * a[n];
      if (tid < 128) wha_s[m] = acc; else wha_d[m] = acc;
    }
    __syncthreads();
    {
      int k = tid & 127;
      const float* wl = W_lin + k * D;
      const float* wha = (tid < 128) ? wha_s : wha_d;
      float acc = 0.f;
      for (int m = 0; m < D; ++m) acc += wl[m] * wha[m];
      if (tid < 128) scs[k] = acc; else scd[k] = acc;
    }
    __syncthreads();
    if (tid < 2) {
      const float* wha = tid ? wha_d : wha_s;
      float a = 0.f;
      for (int k = 0; k < D; ++k) a += b_lin[k] * wha[k];
      sbuf[h * 2 + tid] = a;
    }
    {
      int s = (tid >> 6) & 3, q = (tid >> 4) & 3, n0 = tid & 15;
      int kbase = s * 32 + q * 8;
      float vals[8];
      #pragma unroll
      for (int j = 0; j < 8; ++j)
        vals[j] = (n0 == 0) ? scs[kbase + j] : ((n0 == 1) ? scd[kbase + j] : 0.f);
      unsigned int w[4];
      #pragma unroll
      for (int p = 0; p < 4; ++p)
        w[p] = (unsigned int)f2b(vals[2 * p]) | ((unsigned int)f2b(vals[2 * p + 1]) << 16);
      Bpack[h * 2304 + 2048 + tid] = make_uint4(w[0], w[1], w[2], w[3]);
    }
  } else if (bx < 29) {
    int t = (bx - 27) * 256 + tid;
    if (t < NH * D) {
      int h = t / D, n = t - h * D;
      float acc = 0.f;
      for (int k = 0; k < D; ++k) acc += b_lin[k] * W_heads[h * D * D + k * D + n];
      bcomb[t] = acc;
    }
  } else {
    int i = (bx - 29) * 256 + tid;
    if (i < NN) counts[i] = 0;
  }
}

// ---------------------------------------------------------------------------
// mfma_h3s v2: grid 782 blocks; x staged ONCE; heads looped internally with
// double-buffered 9-fragment B prefetch (software pipeline, ~155 VGPR via
// __launch_bounds__(256,3)). Also fuses the edge histogram (3 edges/thread)
// and the score columns (nt==8). Epilogue: all 3 head-sections of each row
// written by this block (temporally close -> full-line L2 writes).
// ---------------------------------------------------------------------------
__global__ __launch_bounds__(256, 3) void mfma_h3s(const float* __restrict__ x,
                                                   const uint4* __restrict__ Bpack,
                                                   const float* __restrict__ bcomb,
                                                   const float* __restrict__ sbuf,
                                                   const int* __restrict__ ei,
                                                   int* __restrict__ counts,
                                                   unsigned short* __restrict__ h3,
                                                   float* __restrict__ s_src,
                                                   float* __restrict__ s_dst) {
  const int row0 = blockIdx.x * 64;
  const int tid = threadIdx.x;
  // fused histogram: 782*256 = 200192 threads, 3 edges each >= NE
  #pragma unroll
  for (int j = 0; j < 3; ++j) {
    int e = blockIdx.x * 256 + tid + j * GEMM_THREADS;
    if (e < NE) atomicAdd(&counts[ei[NE + e]], 1);
  }
  __shared__ __align__(16) unsigned short As[64][136];
  #pragma unroll
  for (int it = 0; it < 8; ++it) {
    int idx = tid + it * 256;
    int m = idx >> 5, k4 = idx & 31;
    int row = row0 + m;
    float4 v = make_float4(0.f, 0.f, 0.f, 0.f);
    if (row < NN) v = ((const float4*)(x + (size_t)row * D))[k4];
    uint2 pk;
    pk.x = (unsigned int)f2b(v.x) | ((unsigned int)f2b(v.y) << 16);
    pk.y = (unsigned int)f2b(v.z) | ((unsigned int)f2b(v.w) << 16);
    *((uint2*)&As[m][k4 * 4]) = pk;
  }
  __syncthreads();
  const int wv = tid >> 6;
  const int lane = tid & 63;
  const int n0 = lane & 15, q = lane >> 4;

  // hoist the 4 A-fragments (shared by all heads)
  bf16x8 a4[4];
  #pragma unroll
  for (int s = 0; s < 4; ++s)
    a4[s] = *(const bf16x8*)&As[wv * 16 + n0][s * 32 + q * 8];

  for (int head = 0; head < NH; ++head) {
    const bf16x8* Bp = (const bf16x8*)(Bpack + head * 2304);
    const int boff = q * 16 + n0;
    bf16x8 b2[2][9];
    #pragma unroll
    for (int nt = 0; nt < 9; ++nt) b2[0][nt] = Bp[(nt * 4 + 0) * 64 + boff];

    f32x4 acc[9];
    #pragma unroll
    for (int nt = 0; nt < 9; ++nt) acc[nt] = (f32x4){0.f, 0.f, 0.f, 0.f};

    #pragma unroll
    for (int s = 0; s < 4; ++s) {
      if (s < 3) {
        #pragma unroll
        for (int nt = 0; nt < 9; ++nt)
          b2[(s + 1) & 1][nt] = Bp[(nt * 4 + s + 1) * 64 + boff];
      }
      #pragma unroll
      for (int nt = 0; nt < 9; ++nt)
        acc[nt] = __builtin_amdgcn_mfma_f32_16x16x32_bf16(a4[s], b2[s & 1][nt],
                                                          acc[nt], 0, 0, 0);
    }
    const float* bc = bcomb + head * D;
    unsigned short* H = h3 + (size_t)head * D;
    #pragma unroll
    for (int nt = 0; nt < 8; ++nt) {
      int col = nt * 16 + n0;
      float bv = bc[col];
      #pragma unroll
      for (int r = 0; r < 4; ++r) {
        int row = row0 + wv * 16 + q * 4 + r;
        if (row < NN) H[(size_t)row * (NH * D) + col] = f2b(acc[nt][r] + bv);
      }
    }
    // score columns: n0==0 -> s_src, n0==1 -> s_dst  (C/D row = q*4+r)
    if (n0 < 2) {
      float sb = sbuf[head * 2 + n0];
      float* Sout = n0 ? s_dst : s_src;
      #pragma unroll
      for (int r = 0; r < 4; ++r) {
        int row = row0 + wv * 16 + q * 4 + r;
        if (row < NN) Sout[row * NH + head] = acc[8][r] + sb;
      }
    }
  }
}

// --------------------------- CSR scan (2 launches) -------------------------
__global__ __launch_bounds__(256) void scan1(const int* __restrict__ counts,
                                             int* __restrict__ expart,
                                             int* __restrict__ blocksums) {
  __shared__ int tmp[2][256];
  int i = blockIdx.x * 256 + threadIdx.x;
  int t = threadIdx.x;
  int v = (i < NN) ? counts[i] : 0;
  tmp[0][t] = v;
  __syncthreads();
  int cur = 0;
  #pragma unroll
  for (int off = 1; off < 256; off <<= 1) {
    int nv = tmp[cur][t] + (t >= off ? tmp[cur][t - off] : 0);
    tmp[1 - cur][t] = nv;
    cur = 1 - cur;
    __syncthreads();
  }
  if (i < NN) expart[i] = tmp[cur][t] - v;
  if (t == 255) blocksums[blockIdx.x] = tmp[cur][t];
}

// scan3b: merged scan2+scan3 — each block reduces blocksums[0..bx) inline.
__global__ __launch_bounds__(256) void scan3b(const int* __restrict__ expart,
                                              const int* __restrict__ blocksums,
                                              int* __restrict__ row_start,
                                              int* __restrict__ cursor) {
  __shared__ int red[256];
  const int bx = blockIdx.x;
  const int t = threadIdx.x;
  red[t] = (t < bx) ? blocksums[t] : 0;    // bx <= 195 < 256
  __syncthreads();
  #pragma unroll
  for (int off = 128; off > 0; off >>= 1) {
    if (t < off) red[t] += red[t + off];
    __syncthreads();
  }
  int base = red[0];
  int i = bx * 256 + t;
  if (i < NN) {
    int v = expart[i] + base;
    row_start[i] = v;
    cursor[i] = v;
  }
  if (i == 0) row_start[NN] = NE;
}

// ---------------------------------------------------------------------------
// Scatter: slots[slot] = { src(16b) | ew_bf16(16b), p0, p1, p2 }.
// ---------------------------------------------------------------------------
__global__ __launch_bounds__(256) void scatter(const int* __restrict__ ei,
                                               const int* __restrict__ eid,
                                               const float* __restrict__ ddi,
                                               const float* __restrict__ emb,
                                               const float* __restrict__ s_src,
                                               const float* __restrict__ s_dst,
                                               int* __restrict__ cursor,
                                               float4* __restrict__ slots) {
  int e = blockIdx.x * 256 + threadIdx.x;
  if (e >= NE) return;
  int src = ei[e], dst = ei[NE + e];
  int slot = atomicAdd(&cursor[dst], 1);
  float ew = emb[eid[e]] - ddi[e];
  float p[NH];
  #pragma unroll
  for (int hd = 0; hd < NH; ++hd) {
    float v = s_src[src * NH + hd] + s_dst[dst * NH + hd];
    v = v > 0.f ? v : 0.2f * v;
    p[hd] = __expf(v);   // no max-subtraction: |v| <= ~10, exp safe in fp32
  }
  unsigned int se = (unsigned int)src | ((unsigned int)f2b(ew) << 16);
  slots[slot] = make_float4(__uint_as_float(se), p[0], p[1], p[2]);
}

// ---------------------------------------------------------------------------
// Gather v8 (proven): one wave per dst, half-wave even/odd slots, 2x unroll.
// ---------------------------------------------------------------------------
__global__ __launch_bounds__(64) void gather8(const int* __restrict__ row_start,
                                              const float4* __restrict__ slots,
                                              const unsigned short* __restrict__ h3,
                                              const float* __restrict__ bias_heads,
                                              float* __restrict__ out) {
  const int dst = blockIdx.x;
  const int lane = threadIdx.x;          // 0..63
  const int half = lane >> 5;
  const int c = (lane & 31) * 4;         // channel base (4 channels per lane)
  const int beg = row_start[dst], end = row_start[dst + 1];
  float a0[4] = {0.f, 0.f, 0.f, 0.f};
  float a1[4] = {0.f, 0.f, 0.f, 0.f};
  float a2[4] = {0.f, 0.f, 0.f, 0.f};
  float d0 = 0.f, d1 = 0.f, d2 = 0.f;
  int s = beg + half;
  for (; s + 2 < end; s += 4) {
    float4 A = slots[s];
    float4 B = slots[s + 2];
    unsigned int seA = __float_as_uint(A.x);
    unsigned int seB = __float_as_uint(B.x);
    const unsigned short* ha = h3 + (size_t)(seA & 0xffffu) * (NH * D);
    const unsigned short* hb = h3 + (size_t)(seB & 0xffffu) * (NH * D);
    float ewA = bhi(seA), ewB = bhi(seB);
    uint2 ua0 = *(const uint2*)&ha[c];
    uint2 ua1 = *(const uint2*)&ha[D + c];
    uint2 ua2 = *(const uint2*)&ha[2 * D + c];
    uint2 ub0 = *(const uint2*)&hb[c];
    uint2 ub1 = *(const uint2*)&hb[D + c];
    uint2 ub2 = *(const uint2*)&hb[2 * D + c];
    float wa0 = A.y * ewA, wa1 = A.z * ewA, wa2 = A.w * ewA;
    float wb0 = B.y * ewB, wb1 = B.z * ewB, wb2 = B.w * ewB;
    a0[0] += wa0 * blo(ua0.x) + wb0 * blo(ub0.x);
    a0[1] += wa0 * bhi(ua0.x) + wb0 * bhi(ub0.x);
    a0[2] += wa0 * blo(ua0.y) + wb0 * blo(ub0.y);
    a0[3] += wa0 * bhi(ua0.y) + wb0 * bhi(ub0.y);
    a1[0] += wa1 * blo(ua1.x) + wb1 * blo(ub1.x);
    a1[1] += wa1 * bhi(ua1.x) + wb1 * bhi(ub1.x);
    a1[2] += wa1 * blo(ua1.y) + wb1 * blo(ub1.y);
    a1[3] += wa1 * bhi(ua1.y) + wb1 * bhi(ub1.y);
    a2[0] += wa2 * blo(ua2.x) + wb2 * blo(ub2.x);
    a2[1] += wa2 * bhi(ua2.x) + wb2 * bhi(ub2.x);
    a2[2] += wa2 * blo(ua2.y) + wb2 * blo(ub2.y);
    a2[3] += wa2 * bhi(ua2.y) + wb2 * bhi(ub2.y);
    d0 += A.y + B.y;
    d1 += A.z + B.z;
    d2 += A.w + B.w;
  }
  if (s < end) {
    float4 A = slots[s];
    unsigned int seA = __float_as_uint(A.x);
    const unsigned short* hp = h3 + (size_t)(seA & 0xffffu) * (NH * D);
    float ew = bhi(seA);
    uint2 u0 = *(const uint2*)&hp[c];
    uint2 u1 = *(const uint2*)&hp[D + c];
    uint2 u2 = *(const uint2*)&hp[2 * D + c];
    float w0 = A.y * ew, w1 = A.z * ew, w2 = A.w * ew;
    a0[0] += w0 * blo(u0.x); a0[1] += w0 * bhi(u0.x);
    a0[2] += w0 * blo(u0.y); a0[3] += w0 * bhi(u0.y);
    a1[0] += w1 * blo(u1.x); a1[1] += w1 * bhi(u1.x);
    a1[2] += w1 * blo(u1.y); a1[3] += w1 * bhi(u1.y);
    a2[0] += w2 * blo(u2.x); a2[1] += w2 * bhi(u2.x);
    a2[2] += w2 * blo(u2.y); a2[3] += w2 * bhi(u2.y);
    d0 += A.y; d1 += A.z; d2 += A.w;
  }
  #pragma unroll
  for (int j = 0; j < 4; ++j) {
    a0[j] += __shfl_xor(a0[j], 32, 64);
    a1[j] += __shfl_xor(a1[j], 32, 64);
    a2[j] += __shfl_xor(a2[j], 32, 64);
  }
  d0 += __shfl_xor(d0, 32, 64);
  d1 += __shfl_xor(d1, 32, 64);
  d2 += __shfl_xor(d2, 32, 64);
  if (half == 0) {
    float r0 = 1.f / fmaxf(d0, 1e-16f);
    float r1 = 1.f / fmaxf(d1, 1e-16f);
    float r2 = 1.f / fmaxf(d2, 1e-16f);
    float4 b0 = ((const float4*)bias_heads)[lane & 31];
    float4 b1 = ((const float4*)bias_heads)[32 + (lane & 31)];
    float4 b2 = ((const float4*)bias_heads)[64 + (lane & 31)];
    float4 o;
    o.x = (a0[0] * r0 + a1[0] * r1 + a2[0] * r2 + b0.x + b1.x + b2.x) * (1.f / 3.f);
    o.y = (a0[1] * r0 + a1[1] * r1 + a2[1] * r2 + b0.y + b1.y + b2.y) * (1.f / 3.f);
    o.z = (a0[2] * r0 + a1[2] * r1 + a2[2] * r2 + b0.z + b1.z + b2.z) * (1.f / 3.f);
    o.w = (a0[3] * r0 + a1[3] * r1 + a2[3] * r2 + b0.w + b1.w + b2.w) * (1.f / 3.f);
    *((float4*)&out[(size_t)dst * D + c]) = o;
  }
}

// ---------------------------------------------------------------------------
extern "C" void kernel_launch(void* const* d_in, const int* in_sizes, int n_in,
                              void* d_out, int out_size, void* d_ws, size_t ws_size,
                              hipStream_t stream) {
  const float* x          = (const float*)d_in[0];
  const int*   ei         = (const int*)d_in[1];
  const int*   eid        = (const int*)d_in[2];
  const float* ddi        = (const float*)d_in[3];
  const float* W_lin      = (const float*)d_in[4];
  const float* b_lin      = (const float*)d_in[5];
  const float* emb        = (const float*)d_in[6];
  const float* W_heads    = (const float*)d_in[7];
  const float* att_src    = (const float*)d_in[8];
  const float* att_dst    = (const float*)d_in[9];
  const float* bias_heads = (const float*)d_in[10];
  float* out = (float*)d_out;

  // workspace layout (16B-aligned chunks first)
  float4* slots  = (float4*)d_ws;                              // NE
  uint4*  Bpack  = (uint4*)(slots + NE);                       // NH*2304
  unsigned short* h3 = (unsigned short*)(Bpack + NH * 2304);   // NN*NH*D bf16
  float*  bcomb  = (float*)(h3 + (size_t)NN * NH * D);         // NH*D
  float*  sbuf   = bcomb + NH * D;                             // 8
  float*  s_src  = sbuf + 8;                                   // NN*NH
  float*  s_dst  = s_src + NN * NH;                            // NN*NH
  int*    counts = (int*)(s_dst + NN * NH);                    // NN (zeroed in pack_all)
  int*    expart = counts + NN;                                // NN
  int*    bsums  = expart + NN;                                // 256
  int*    rstart = bsums + 256;                                // NN+1
  int*    cursor = rstart + NN + 1;                            // NN

  const int edgeBlocks = (NE + 255) / 256;

  // 1. Bpack + score cols + bcomb + sbuf + zero counts
  pack_all<<<29 + SCAN_BLOCKS, 256, 0, stream>>>(W_lin, W_heads, att_src, att_dst,
                                                 b_lin, Bpack, bcomb, sbuf, counts);
  // 2. h3 (all heads, x staged once, pipelined B) + scores + edge histogram
  mfma_h3s<<<GEMM_BLOCKS, 256, 0, stream>>>(x, Bpack, bcomb, sbuf,
                                            ei, counts, h3, s_src, s_dst);
  // 3. CSR scan (2 launches)
  scan1<<<SCAN_BLOCKS, 256, 0, stream>>>(counts, expart, bsums);
  scan3b<<<SCAN_BLOCKS, 256, 0, stream>>>(expart, bsums, rstart, cursor);
  // 4. scatter edges into CSR (int cursor atomic only; src+ew packed)
  scatter<<<edgeBlocks, 256, 0, stream>>>(ei, eid, ddi, emb, s_src, s_dst, cursor,
                                          slots);
  // 5. per-dst gather: 1 wave/dst, 4 edges in flight, no atomics
  gather8<<<NN, 64, 0, stream>>>(rstart, slots, h3, bias_heads, out);
}

// Round 13
// 261.254 us; speedup vs baseline: 1.0149x; 1.0149x over previous
//
#include <hip/hip_runtime.h>
#include <math.h>

#define NN 50000
#define NE 600000
#define D 128
#define NH 3
#define SCAN_BLOCKS ((NN + 255) / 256)   // 196
#define GEMM_BLOCKS ((NN + 63) / 64)     // 782
#define GEMM_THREADS (GEMM_BLOCKS * 256) // 200192

typedef short bf16x8 __attribute__((ext_vector_type(8)));
typedef float f32x4 __attribute__((ext_vector_type(4)));

__device__ __forceinline__ unsigned short f2b(float f) {
  unsigned int u = __float_as_uint(f);
  u += 0x7FFF + ((u >> 16) & 1);          // round-to-nearest-even
  return (unsigned short)(u >> 16);
}
__device__ __forceinline__ float blo(unsigned int u) {
  return __uint_as_float(u << 16);
}
__device__ __forceinline__ float bhi(unsigned int u) {
  return __uint_as_float(u & 0xffff0000u);
}

// ---------------------------------------------------------------------------
// pack_all: one kernel, block-role dispatch (unchanged, proven r11-r12).
// ---------------------------------------------------------------------------
__global__ __launch_bounds__(256) void pack_all(const float* __restrict__ W_lin,
                                                const float* __restrict__ W_heads,
                                                const float* __restrict__ att_src,
                                                const float* __restrict__ att_dst,
                                                const float* __restrict__ b_lin,
                                                uint4* __restrict__ Bpack,
                                                float* __restrict__ bcomb,
                                                float* __restrict__ sbuf,
                                                int* __restrict__ counts) {
  const int bx = blockIdx.x;
  const int tid = threadIdx.x;
  if (bx < 24) {
    int u = bx * 256 + tid;            // < 6144
    int h = u >> 11, r = u & 2047;
    int nt = r >> 8, s = (r >> 6) & 3, q = (r >> 4) & 3, n0 = r & 15;
    int kbase = s * 32 + q * 8;
    int n = nt * 16 + n0;
    const float* wl = W_lin + kbase * D;
    const float* wh = W_heads + h * D * D + n;
    float vals[8];
    #pragma unroll
    for (int j = 0; j < 8; ++j) vals[j] = 0.f;
    for (int m = 0; m < D; ++m) {
      float whv = wh[m * D];
      #pragma unroll
      for (int j = 0; j < 8; ++j) vals[j] += wl[j * D + m] * whv;
    }
    unsigned int w[4];
    #pragma unroll
    for (int p = 0; p < 4; ++p)
      w[p] = (unsigned int)f2b(vals[2 * p]) | ((unsigned int)f2b(vals[2 * p + 1]) << 16);
    Bpack[h * 2304 + r] = make_uint4(w[0], w[1], w[2], w[3]);
  } else if (bx < 27) {
    const int h = bx - 24;
    __shared__ float wha_s[128], wha_d[128], scs[128], scd[128];
    {
      int m = tid & 127;
      const float* W = W_heads + h * D * D + m * D;
      const float* a = (tid < 128) ? (att_src + h * D) : (att_dst + h * D);
      float acc = 0.f;
      for (int n = 0; n < D; ++n) acc += W[n] * a[n];
      if (tid < 128) wha_s[m] = acc; else wha_d[m] = acc;
    }
    __syncthreads();
    {
      int k = tid & 127;
      const float* wl = W_lin + k * D;
      const float* wha = (tid < 128) ? wha_s : wha_d;
      float acc = 0.f;
      for (int m = 0; m < D; ++m) acc += wl[m] * wha[m];
      if (tid < 128) scs[k] = acc; else scd[k] = acc;
    }
    __syncthreads();
    if (tid < 2) {
      const float* wha = tid ? wha_d : wha_s;
      float a = 0.f;
      for (int k = 0; k < D; ++k) a += b_lin[k] * wha[k];
      sbuf[h * 2 + tid] = a;
    }
    {
      int s = (tid >> 6) & 3, q = (tid >> 4) & 3, n0 = tid & 15;
      int kbase = s * 32 + q * 8;
      float vals[8];
      #pragma unroll
      for (int j = 0; j < 8; ++j)
        vals[j] = (n0 == 0) ? scs[kbase + j] : ((n0 == 1) ? scd[kbase + j] : 0.f);
      unsigned int w[4];
      #pragma unroll
      for (int p = 0; p < 4; ++p)
        w[p] = (unsigned int)f2b(vals[2 * p]) | ((unsigned int)f2b(vals[2 * p + 1]) << 16);
      Bpack[h * 2304 + 2048 + tid] = make_uint4(w[0], w[1], w[2], w[3]);
    }
  } else if (bx < 29) {
    int t = (bx - 27) * 256 + tid;
    if (t < NH * D) {
      int h = t / D, n = t - h * D;
      float acc = 0.f;
      for (int k = 0; k < D; ++k) acc += b_lin[k] * W_heads[h * D * D + k * D + n];
      bcomb[t] = acc;
    }
  } else {
    int i = (bx - 29) * 256 + tid;
    if (i < NN) counts[i] = 0;
  }
}

// ---------------------------------------------------------------------------
// mfma_h3s v3: grid 782; x staged once; heads looped with double-buffered B
// prefetch. NEW: epilogue stages each head's 64x128 bf16 tile in the (dead)
// As LDS buffer, then writes h3 with 4 coalesced uint4 stores per thread
// (full 256B lines) instead of 96 scattered 2-byte stores. Histogram fused.
// ---------------------------------------------------------------------------
__global__ __launch_bounds__(256) void mfma_h3s(const float* __restrict__ x,
                                                const uint4* __restrict__ Bpack,
                                                const float* __restrict__ bcomb,
                                                const float* __restrict__ sbuf,
                                                const int* __restrict__ ei,
                                                int* __restrict__ counts,
                                                unsigned short* __restrict__ h3,
                                                float* __restrict__ s_src,
                                                float* __restrict__ s_dst) {
  const int row0 = blockIdx.x * 64;
  const int tid = threadIdx.x;
  // fused histogram: 782*256 = 200192 threads, 3 edges each >= NE
  #pragma unroll
  for (int j = 0; j < 3; ++j) {
    int e = blockIdx.x * 256 + tid + j * GEMM_THREADS;
    if (e < NE) atomicAdd(&counts[ei[NE + e]], 1);
  }
  __shared__ __align__(16) unsigned short As[64][136];
  #pragma unroll
  for (int it = 0; it < 8; ++it) {
    int idx = tid + it * 256;
    int m = idx >> 5, k4 = idx & 31;
    int row = row0 + m;
    float4 v = make_float4(0.f, 0.f, 0.f, 0.f);
    if (row < NN) v = ((const float4*)(x + (size_t)row * D))[k4];
    uint2 pk;
    pk.x = (unsigned int)f2b(v.x) | ((unsigned int)f2b(v.y) << 16);
    pk.y = (unsigned int)f2b(v.z) | ((unsigned int)f2b(v.w) << 16);
    *((uint2*)&As[m][k4 * 4]) = pk;
  }
  __syncthreads();
  const int wv = tid >> 6;
  const int lane = tid & 63;
  const int n0 = lane & 15, q = lane >> 4;

  // hoist the 4 A-fragments (shared by all heads); As becomes reusable after
  // the next barrier.
  bf16x8 a4[4];
  #pragma unroll
  for (int s = 0; s < 4; ++s)
    a4[s] = *(const bf16x8*)&As[wv * 16 + n0][s * 32 + q * 8];

  for (int head = 0; head < NH; ++head) {
    const bf16x8* Bp = (const bf16x8*)(Bpack + head * 2304);
    const int boff = q * 16 + n0;
    bf16x8 b2[2][9];
    #pragma unroll
    for (int nt = 0; nt < 9; ++nt) b2[0][nt] = Bp[(nt * 4 + 0) * 64 + boff];

    f32x4 acc[9];
    #pragma unroll
    for (int nt = 0; nt < 9; ++nt) acc[nt] = (f32x4){0.f, 0.f, 0.f, 0.f};

    #pragma unroll
    for (int s = 0; s < 4; ++s) {
      if (s < 3) {
        #pragma unroll
        for (int nt = 0; nt < 9; ++nt)
          b2[(s + 1) & 1][nt] = Bp[(nt * 4 + s + 1) * 64 + boff];
      }
      #pragma unroll
      for (int nt = 0; nt < 9; ++nt)
        acc[nt] = __builtin_amdgcn_mfma_f32_16x16x32_bf16(a4[s], b2[s & 1][nt],
                                                          acc[nt], 0, 0, 0);
    }
    // barrier: head 0 -> all a4 hoisted; head >0 -> previous read phase done
    __syncthreads();
    const float* bc = bcomb + head * D;
    #pragma unroll
    for (int nt = 0; nt < 8; ++nt) {
      int col = nt * 16 + n0;
      float bv = bc[col];
      #pragma unroll
      for (int r = 0; r < 4; ++r)
        As[wv * 16 + q * 4 + r][col] = f2b(acc[nt][r] + bv);
    }
    // score columns: n0==0 -> s_src, n0==1 -> s_dst  (C/D row = q*4+r)
    if (n0 < 2) {
      float sb = sbuf[head * 2 + n0];
      float* Sout = n0 ? s_dst : s_src;
      #pragma unroll
      for (int r = 0; r < 4; ++r) {
        int row = row0 + wv * 16 + q * 4 + r;
        if (row < NN) Sout[row * NH + head] = acc[8][r] + sb;
      }
    }
    __syncthreads();
    // coalesced write-out: 1024 uint4 (16 per row), 4 per thread
    #pragma unroll
    for (int i = 0; i < 4; ++i) {
      int idx = tid + i * 256;          // 0..1023
      int row = idx >> 4, c16 = idx & 15;
      int grow = row0 + row;
      if (grow < NN)
        *((uint4*)&h3[(size_t)grow * (NH * D) + head * D + c16 * 8]) =
            *((const uint4*)&As[row][c16 * 8]);
    }
  }
}

// --------------------------- CSR scan (2 launches) -------------------------
__global__ __launch_bounds__(256) void scan1(const int* __restrict__ counts,
                                             int* __restrict__ expart,
                                             int* __restrict__ blocksums) {
  __shared__ int tmp[2][256];
  int i = blockIdx.x * 256 + threadIdx.x;
  int t = threadIdx.x;
  int v = (i < NN) ? counts[i] : 0;
  tmp[0][t] = v;
  __syncthreads();
  int cur = 0;
  #pragma unroll
  for (int off = 1; off < 256; off <<= 1) {
    int nv = tmp[cur][t] + (t >= off ? tmp[cur][t - off] : 0);
    tmp[1 - cur][t] = nv;
    cur = 1 - cur;
    __syncthreads();
  }
  if (i < NN) expart[i] = tmp[cur][t] - v;
  if (t == 255) blocksums[blockIdx.x] = tmp[cur][t];
}

// scan3b: merged scan2+scan3 — each block reduces blocksums[0..bx) inline.
__global__ __launch_bounds__(256) void scan3b(const int* __restrict__ expart,
                                              const int* __restrict__ blocksums,
                                              int* __restrict__ row_start,
                                              int* __restrict__ cursor) {
  __shared__ int red[256];
  const int bx = blockIdx.x;
  const int t = threadIdx.x;
  red[t] = (t < bx) ? blocksums[t] : 0;    // bx <= 195 < 256
  __syncthreads();
  #pragma unroll
  for (int off = 128; off > 0; off >>= 1) {
    if (t < off) red[t] += red[t + off];
    __syncthreads();
  }
  int base = red[0];
  int i = bx * 256 + t;
  if (i < NN) {
    int v = expart[i] + base;
    row_start[i] = v;
    cursor[i] = v;
  }
  if (i == 0) row_start[NN] = NE;
}

// ---------------------------------------------------------------------------
// Scatter: slots[slot] = { src(16b) | ew_bf16(16b), p0, p1, p2 }.
// ---------------------------------------------------------------------------
__global__ __launch_bounds__(256) void scatter(const int* __restrict__ ei,
                                               const int* __restrict__ eid,
                                               const float* __restrict__ ddi,
                                               const float* __restrict__ emb,
                                               const float* __restrict__ s_src,
                                               const float* __restrict__ s_dst,
                                               int* __restrict__ cursor,
                                               float4* __restrict__ slots) {
  int e = blockIdx.x * 256 + threadIdx.x;
  if (e >= NE) return;
  int src = ei[e], dst = ei[NE + e];
  int slot = atomicAdd(&cursor[dst], 1);
  float ew = emb[eid[e]] - ddi[e];
  float p[NH];
  #pragma unroll
  for (int hd = 0; hd < NH; ++hd) {
    float v = s_src[src * NH + hd] + s_dst[dst * NH + hd];
    v = v > 0.f ? v : 0.2f * v;
    p[hd] = __expf(v);   // no max-subtraction: |v| <= ~10, exp safe in fp32
  }
  unsigned int se = (unsigned int)src | ((unsigned int)f2b(ew) << 16);
  slots[slot] = make_float4(__uint_as_float(se), p[0], p[1], p[2]);
}

// ---------------------------------------------------------------------------
// Gather v8 (proven): one wave per dst, half-wave even/odd slots, 2x unroll.
// ---------------------------------------------------------------------------
__global__ __launch_bounds__(64) void gather8(const int* __restrict__ row_start,
                                              const float4* __restrict__ slots,
                                              const unsigned short* __restrict__ h3,
                                              const float* __restrict__ bias_heads,
                                              float* __restrict__ out) {
  const int dst = blockIdx.x;
  const int lane = threadIdx.x;          // 0..63
  const int half = lane >> 5;
  const int c = (lane & 31) * 4;         // channel base (4 channels per lane)
  const int beg = row_start[dst], end = row_start[dst + 1];
  float a0[4] = {0.f, 0.f, 0.f, 0.f};
  float a1[4] = {0.f, 0.f, 0.f, 0.f};
  float a2[4] = {0.f, 0.f, 0.f, 0.f};
  float d0 = 0.f, d1 = 0.f, d2 = 0.f;
  int s = beg + half;
  for (; s + 2 < end; s += 4) {
    float4 A = slots[s];
    float4 B = slots[s + 2];
    unsigned int seA = __float_as_uint(A.x);
    unsigned int seB = __float_as_uint(B.x);
    const unsigned short* ha = h3 + (size_t)(seA & 0xffffu) * (NH * D);
    const unsigned short* hb = h3 + (size_t)(seB & 0xffffu) * (NH * D);
    float ewA = bhi(seA), ewB = bhi(seB);
    uint2 ua0 = *(const uint2*)&ha[c];
    uint2 ua1 = *(const uint2*)&ha[D + c];
    uint2 ua2 = *(const uint2*)&ha[2 * D + c];
    uint2 ub0 = *(const uint2*)&hb[c];
    uint2 ub1 = *(const uint2*)&hb[D + c];
    uint2 ub2 = *(const uint2*)&hb[2 * D + c];
    float wa0 = A.y * ewA, wa1 = A.z * ewA, wa2 = A.w * ewA;
    float wb0 = B.y * ewB, wb1 = B.z * ewB, wb2 = B.w * ewB;
    a0[0] += wa0 * blo(ua0.x) + wb0 * blo(ub0.x);
    a0[1] += wa0 * bhi(ua0.x) + wb0 * bhi(ub0.x);
    a0[2] += wa0 * blo(ua0.y) + wb0 * blo(ub0.y);
    a0[3] += wa0 * bhi(ua0.y) + wb0 * bhi(ub0.y);
    a1[0] += wa1 * blo(ua1.x) + wb1 * blo(ub1.x);
    a1[1] += wa1 * bhi(ua1.x) + wb1 * bhi(ub1.x);
    a1[2] += wa1 * blo(ua1.y) + wb1 * blo(ub1.y);
    a1[3] += wa1 * bhi(ua1.y) + wb1 * bhi(ub1.y);
    a2[0] += wa2 * blo(ua2.x) + wb2 * blo(ub2.x);
    a2[1] += wa2 * bhi(ua2.x) + wb2 * bhi(ub2.x);
    a2[2] += wa2 * blo(ua2.y) + wb2 * blo(ub2.y);
    a2[3] += wa2 * bhi(ua2.y) + wb2 * bhi(ub2.y);
    d0 += A.y + B.y;
    d1 += A.z + B.z;
    d2 += A.w + B.w;
  }
  if (s < end) {
    float4 A = slots[s];
    unsigned int seA = __float_as_uint(A.x);
    const unsigned short* hp = h3 + (size_t)(seA & 0xffffu) * (NH * D);
    float ew = bhi(seA);
    uint2 u0 = *(const uint2*)&hp[c];
    uint2 u1 = *(const uint2*)&hp[D + c];
    uint2 u2 = *(const uint2*)&hp[2 * D + c];
    float w0 = A.y * ew, w1 = A.z * ew, w2 = A.w * ew;
    a0[0] += w0 * blo(u0.x); a0[1] += w0 * bhi(u0.x);
    a0[2] += w0 * blo(u0.y); a0[3] += w0 * bhi(u0.y);
    a1[0] += w1 * blo(u1.x); a1[1] += w1 * bhi(u1.x);
    a1[2] += w1 * blo(u1.y); a1[3] += w1 * bhi(u1.y);
    a2[0] += w2 * blo(u2.x); a2[1] += w2 * bhi(u2.x);
    a2[2] += w2 * blo(u2.y); a2[3] += w2 * bhi(u2.y);
    d0 += A.y; d1 += A.z; d2 += A.w;
  }
  #pragma unroll
  for (int j = 0; j < 4; ++j) {
    a0[j] += __shfl_xor(a0[j], 32, 64);
    a1[j] += __shfl_xor(a1[j], 32, 64);
    a2[j] += __shfl_xor(a2[j], 32, 64);
  }
  d0 += __shfl_xor(d0, 32, 64);
  d1 += __shfl_xor(d1, 32, 64);
  d2 += __shfl_xor(d2, 32, 64);
  if (half == 0) {
    float r0 = 1.f / fmaxf(d0, 1e-16f);
    float r1 = 1.f / fmaxf(d1, 1e-16f);
    float r2 = 1.f / fmaxf(d2, 1e-16f);
    float4 b0 = ((const float4*)bias_heads)[lane & 31];
    float4 b1 = ((const float4*)bias_heads)[32 + (lane & 31)];
    float4 b2 = ((const float4*)bias_heads)[64 + (lane & 31)];
    float4 o;
    o.x = (a0[0] * r0 + a1[0] * r1 + a2[0] * r2 + b0.x + b1.x + b2.x) * (1.f / 3.f);
    o.y = (a0[1] * r0 + a1[1] * r1 + a2[1] * r2 + b0.y + b1.y + b2.y) * (1.f / 3.f);
    o.z = (a0[2] * r0 + a1[2] * r1 + a2[2] * r2 + b0.z + b1.z + b2.z) * (1.f / 3.f);
    o.w = (a0[3] * r0 + a1[3] * r1 + a2[3] * r2 + b0.w + b1.w + b2.w) * (1.f / 3.f);
    *((float4*)&out[(size_t)dst * D + c]) = o;
  }
}

// ---------------------------------------------------------------------------
extern "C" void kernel_launch(void* const* d_in, const int* in_sizes, int n_in,
                              void* d_out, int out_size, void* d_ws, size_t ws_size,
                              hipStream_t stream) {
  const float* x          = (const float*)d_in[0];
  const int*   ei         = (const int*)d_in[1];
  const int*   eid        = (const int*)d_in[2];
  const float* ddi        = (const float*)d_in[3];
  const float* W_lin      = (const float*)d_in[4];
  const float* b_lin      = (const float*)d_in[5];
  const float* emb        = (const float*)d_in[6];
  const float* W_heads    = (const float*)d_in[7];
  const float* att_src    = (const float*)d_in[8];
  const float* att_dst    = (const float*)d_in[9];
  const float* bias_heads = (const float*)d_in[10];
  float* out = (float*)d_out;

  // workspace layout (16B-aligned chunks first)
  float4* slots  = (float4*)d_ws;                              // NE
  uint4*  Bpack  = (uint4*)(slots + NE);                       // NH*2304
  unsigned short* h3 = (unsigned short*)(Bpack + NH * 2304);   // NN*NH*D bf16
  float*  bcomb  = (float*)(h3 + (size_t)NN * NH * D);         // NH*D
  float*  sbuf   = bcomb + NH * D;                             // 8
  float*  s_src  = sbuf + 8;                                   // NN*NH
  float*  s_dst  = s_src + NN * NH;                            // NN*NH
  int*    counts = (int*)(s_dst + NN * NH);                    // NN (zeroed in pack_all)
  int*    expart = counts + NN;                                // NN
  int*    bsums  = expart + NN;                                // 256
  int*    rstart = bsums + 256;                                // NN+1
  int*    cursor = rstart + NN + 1;                            // NN

  const int edgeBlocks = (NE + 255) / 256;

  // 1. Bpack + score cols + bcomb + sbuf + zero counts
  pack_all<<<29 + SCAN_BLOCKS, 256, 0, stream>>>(W_lin, W_heads, att_src, att_dst,
                                                 b_lin, Bpack, bcomb, sbuf, counts);
  // 2. h3 (all heads, LDS-staged coalesced stores) + scores + edge histogram
  mfma_h3s<<<GEMM_BLOCKS, 256, 0, stream>>>(x, Bpack, bcomb, sbuf,
                                            ei, counts, h3, s_src, s_dst);
  // 3. CSR scan (2 launches)
  scan1<<<SCAN_BLOCKS, 256, 0, stream>>>(counts, expart, bsums);
  scan3b<<<SCAN_BLOCKS, 256, 0, stream>>>(expart, bsums, rstart, cursor);
  // 4. scatter edges into CSR (int cursor atomic only; src+ew packed)
  scatter<<<edgeBlocks, 256, 0, stream>>>(ei, eid, ddi, emb, s_src, s_dst, cursor,
                                          slots);
  // 5. per-dst gather: 1 wave/dst, 4 edges in flight, no atomics
  gather8<<<NN, 64, 0, stream>>>(rstart, slots, h3, bias_heads, out);
}